// Round 10
// baseline (167.264 us; speedup 1.0000x reference)
//
#include <hip/hip_runtime.h>
#include <hip/hip_bf16.h>

#define E 256
#define H 8
#define HD 32
#define T 768
#define B 4
#define BH 32
// segments: L=[0,300), A=[300,550), V=[550,768)

typedef __attribute__((ext_vector_type(8))) short bf16x8;
typedef __attribute__((ext_vector_type(4))) float f32x4;
typedef __attribute__((ext_vector_type(16))) float f32x16;

__device__ __forceinline__ float b2f(__hip_bfloat16 x) { return __bfloat162float(x); }

__device__ __forceinline__ unsigned short f2bf_u(float x) {
    __hip_bfloat16 h = __float2bfloat16(x);
    return *(unsigned short*)&h;
}
__device__ __forceinline__ float bfu2f(unsigned short u) {
    return __uint_as_float(((unsigned int)u) << 16);
}

// Inline per-wave dtype detection: fp32 input read as bf16 -> garbage
// exponents in query[0..255]. 4 strided u16 loads/lane + __any. Wave-uniform.
__device__ __forceinline__ int detect_f32(const void* query) {
    const unsigned short* q = (const unsigned short*)query;
    int lane = threadIdx.x & 63;
    int bad = 0;
    #pragma unroll
    for (int i = 0; i < 4; ++i) {
        float v = bfu2f(q[lane + i * 64]);
        bad |= (!(v == v) || fabsf(v) > 1e4f) ? 1 : 0;
    }
    return __any(bad) ? 1 : 0;
}

// split fp32[8] -> bf16 hi + lo fragments (RTNE)
__device__ __forceinline__ void f8_split(const float* v, bf16x8& h, bf16x8& l) {
    #pragma unroll
    for (int e = 0; e < 8; ++e) {
        unsigned short hu = f2bf_u(v[e]);
        h[e] = (short)hu;
        l[e] = (short)f2bf_u(v[e] - bfu2f(hu));
    }
}

#define MFMA3(ACC, AH, AL, BH_, BL_)                                         \
    ACC = __builtin_amdgcn_mfma_f32_16x16x32_bf16(AH, BH_, ACC, 0, 0, 0);    \
    ACC = __builtin_amdgcn_mfma_f32_16x16x32_bf16(AH, BL_, ACC, 0, 0, 0);    \
    ACC = __builtin_amdgcn_mfma_f32_16x16x32_bf16(AL, BH_, ACC, 0, 0, 0);

#define MFMA3W(ACC, AH, AL, BH_, BL_)                                        \
    ACC = __builtin_amdgcn_mfma_f32_32x32x16_bf16(AH, BH_, ACC, 0, 0, 0);    \
    ACC = __builtin_amdgcn_mfma_f32_32x32x16_bf16(AH, BL_, ACC, 0, 0, 0);    \
    ACC = __builtin_amdgcn_mfma_f32_32x32x16_bf16(AL, BH_, ACC, 0, 0, 0);

__device__ __forceinline__ bf16x8 mk8(int a, int b, int c, int d) {
    union { int i[4]; bf16x8 v; } u;
    u.i[0] = a; u.i[1] = b; u.i[2] = c; u.i[3] = d;
    return u.v;
}

// dtype-agnostic scalar load: f32 ? float : bf16
__device__ __forceinline__ float ldu(const void* p, size_t i, int f32) {
    if (f32) return ((const float*)p)[i];
    return b2f(((const __hip_bfloat16*)p)[i]);
}

// G_i row loader (branch-summed s_*_w blocks)
__device__ __forceinline__ float gsum_load(int i, int r2, int r,
                                           const void* sl, const void* sa,
                                           const void* sv, int f32)
{
    size_t base = (size_t)r2 * 1024;
    switch (i) {
        case 0: return ldu(sl, base + r, f32) + ldu(sa, base + r, f32) + ldu(sv, base + r, f32);
        case 1: return ldu(sl, base + 256 + r, f32) + ldu(sa, base + 256 + r, f32);
        case 2: return ldu(sl, base + 512 + r, f32) + ldu(sv, base + 256 + r, f32);
        case 3: return ldu(sa, base + 512 + r, f32) + ldu(sv, base + 512 + r, f32);
        case 4: return ldu(sl, base + 768 + r, f32);
        case 5: return ldu(sa, base + 768 + r, f32);
        default: return ldu(sv, base + 768 + r, f32);
    }
}

// ---------------------------------------------------------------------------
// STAGE 1 (round-28): W conv (0..95) + OWF conv (96..319) + Q GEMM (320..767)
// + bias1 (768..1023).
// Q_i = final_w @ G_i (contraction over r2) is raw-weight-only -> depth 1.
// DT then = ow_i^T-style GEMM over Q at depth 2, removing wcomb2 from stage3
// and the Mtmp/GF round-trips entirely.
// ---------------------------------------------------------------------------
__global__ __launch_bounds__(256) void stage1_kernel(
    const void* query, const void* w,
    const void* sl, const void* sa, const void* sv, const void* outw,
    const void* outb, const void* slb, const void* sab, const void* svb,
    const void* finalw,
    unsigned short* __restrict__ WFh, unsigned short* __restrict__ WFl,
    unsigned short* __restrict__ OWFh, unsigned short* __restrict__ OWFl,
    float* __restrict__ Qbuf, float* __restrict__ c0)
{
    __shared__ float red[256];
    int f32 = detect_f32(query);
    int bid = blockIdx.x;
    if (bid < 320) {
        // ---- conversion branch (W + OWF) ----
        int item = bid * 256 + threadIdx.x;
        if (item < 24576) {                        // W: 768 rows x 32 kg
            int gc = item >> 5, kg = item & 31;
            float v[8];
            if (f32) {
                const float4* p = (const float4*)((const float*)w +
                                   (size_t)gc * 256 + kg * 8);
                *(float4*)&v[0] = p[0];
                *(float4*)&v[4] = p[1];
            } else {
                #pragma unroll
                for (int j = 0; j < 8; ++j)
                    v[j] = ldu(w, (size_t)gc * 256 + kg * 8 + j, 0);
            }
            bf16x8 h, l;
            f8_split(v, h, l);
            int sec = gc >> 8, c = gc & 255;
            int cb = c >> 4, kb = kg >> 2;
            int lane = (c & 15) | ((kg & 3) << 4);
            size_t idx = (((size_t)(sec * 16 + cb) * 8 + kb) * 64 + lane) * 8;
            *(bf16x8*)&WFh[idx] = h;
            *(bf16x8*)&WFl[idx] = l;
        } else if (item < 81920) {                 // OW^T: 7 x 32 kg x 256 c
            int rem = item - 24576;
            int i = rem >> 13;
            int rest = rem & 8191;
            int kg = rest >> 8, c = rest & 255;
            float v[8];
            #pragma unroll
            for (int j = 0; j < 8; ++j)
                v[j] = ldu(outw, (size_t)i * 65536 + (kg * 8 + j) * 256 + c, f32);
            bf16x8 h, l;
            f8_split(v, h, l);
            int cb = c >> 4, kb = kg >> 2;
            int lane = (c & 15) | ((kg & 3) << 4);
            size_t idx = (((size_t)(i * 16 + cb) * 8 + kb) * 64 + lane) * 8;
            *(bf16x8*)&OWFh[idx] = h;
            *(bf16x8*)&OWFl[idx] = l;
        }
    } else if (bid < 768) {
        // ---- Q GEMM branch: Q_i[e][k] = sum_r2 fw[e][r2] * G_i[r2][k] ----
        int unit = bid - 320;
        int kgrp = unit & 3;          // 0..3
        int eb   = (unit >> 2) & 15;  // 0..15 (e block)
        int i    = unit >> 6;         // branch 0..6
        int w_ = threadIdx.x >> 6, lane = threadIdx.x & 63;
        int m = lane & 15, quad = lane >> 4;
        int kblk = kgrp * 4 + w_;     // k block 0..15

        f32x4 acc = {};
        #pragma unroll
        for (int rb2 = 0; rb2 < 8; ++rb2) {
            // A: fw[e][r2], e = eb*16+m (lane row), r2 = rb2*32 + quad*8 + j
            float av[8];
            size_t fo = (size_t)(eb * 16 + m) * 256 + rb2 * 32 + quad * 8;
            if (f32) {
                const float4* p = (const float4*)((const float*)finalw + fo);
                *(float4*)&av[0] = p[0];
                *(float4*)&av[4] = p[1];
            } else {
                #pragma unroll
                for (int j = 0; j < 8; ++j)
                    av[j] = ldu(finalw, fo + j, 0);
            }
            bf16x8 ah, al;
            f8_split(av, ah, al);
            // B: G_i[r2][k], k = kblk*16+m (lane col), r2 = rb2*32 + quad*8 + j
            float bv[8];
            #pragma unroll
            for (int j = 0; j < 8; ++j)
                bv[j] = gsum_load(i, rb2 * 32 + quad * 8 + j, kblk * 16 + m,
                                  sl, sa, sv, f32);
            bf16x8 bh, bl;
            f8_split(bv, bh, bl);
            MFMA3(acc, ah, al, bh, bl)
        }
        #pragma unroll
        for (int rr = 0; rr < 4; ++rr) {
            int e_ = eb * 16 + quad * 4 + rr;
            Qbuf[(size_t)i * 65536 + e_ * 256 + kblk * 16 + m] = acc[rr];
        }
    } else {
        // ---- bias1 branch ----
        int r2 = bid - 768, m = threadIdx.x;
        float acc = 0.f;
        #pragma unroll
        for (int i = 0; i < 7; ++i)
            acc += ldu(outb, i * 256 + m, f32) * gsum_load(i, r2, m, sl, sa, sv, f32);
        red[m] = acc;
        __syncthreads();
        for (int s = 128; s > 0; s >>= 1) {
            if (m < s) red[m] += red[m + s];
            __syncthreads();
        }
        if (m == 0)
            c0[r2] = red[0] + ldu(slb, r2, f32) + ldu(sab, r2, f32) + ldu(svb, r2, f32);
    }
}

// ---------------------------------------------------------------------------
// STAGE 2 (round-28): qkv direct-X (0..575) + DT GEMM (576..1023)
// + bias2 (1024..1279).
// DT_i[c][e] = sum_k ow_i[k][c] * Q_i[e][k]  (A = Q rows direct fp32 gather
// + in-register split; B = OWF fragments unchanged). Writes DT in the
// fragment-major layout stage4 consumes. Replaces wcomb1+wcomb2.
// ---------------------------------------------------------------------------
__global__ __launch_bounds__(256) void stage2_kernel(
    const void* query, const void* key, const void* value,
    const unsigned short* __restrict__ WFh, const unsigned short* __restrict__ WFl,
    const void* bias,
    float* __restrict__ qws,
    unsigned short* __restrict__ KRh, unsigned short* __restrict__ KRl,
    unsigned short* __restrict__ VFh, unsigned short* __restrict__ VFl,
    const unsigned short* __restrict__ OWFh, const unsigned short* __restrict__ OWFl,
    const float* __restrict__ Qbuf,
    unsigned short* __restrict__ DThi, unsigned short* __restrict__ DTlo,
    const float* __restrict__ c0, const void* finalw, const void* finalb,
    float* __restrict__ d0)
{
    __shared__ float red[256];
    int bxx = blockIdx.x;
    if (bxx < 576) {
        // ---- qkv branch (direct-X, full row-strip per block) ----
        int f32 = detect_f32(query);
        int sec = bxx / 192;          // 0..2
        int rb  = bxx % 192;          // 0..191 rowblk
        const void* X = (sec == 0) ? query : (sec == 1) ? key : value;
        int w = threadIdx.x >> 6, lane = threadIdx.x & 63;
        int m = lane & 15, quad = lane >> 4;

        size_t aoff0 = (size_t)(rb * 16 + (lane & 15)) * 256 + quad * 8;

        f32x4 acc[4] = {};
        #pragma unroll
        for (int kb = 0; kb < 8; ++kb) {
            float av[8];
            size_t aoff = aoff0 + kb * 32;
            if (f32) {
                const float4* p = (const float4*)((const float*)X + aoff);
                *(float4*)&av[0] = p[0];
                *(float4*)&av[4] = p[1];
            } else {
                #pragma unroll
                for (int j = 0; j < 8; ++j)
                    av[j] = ldu(X, aoff + j, 0);
            }
            bf16x8 ah, al;
            f8_split(av, ah, al);
            #pragma unroll
            for (int c = 0; c < 4; ++c) {
                int cb = w * 4 + c;
                const unsigned short* Bh = WFh + (((size_t)(sec * 16 + cb) * 8 + kb) * 64 + lane) * 8;
                const unsigned short* Bl = WFl + (((size_t)(sec * 16 + cb) * 8 + kb) * 64 + lane) * 8;
                bf16x8 bh = *(const bf16x8*)Bh;
                bf16x8 bl = *(const bf16x8*)Bl;
                MFMA3(acc[c], ah, al, bh, bl)
            }
        }

        #pragma unroll
        for (int c = 0; c < 4; ++c) {
            int cb = w * 4 + c;
            int c_local = cb * 16 + m;             // col within section
            float bv = ldu(bias, sec * 256 + c_local, f32);
            int h = c_local >> 5, hd = c_local & 31;

            if (sec == 0) {
                #pragma unroll
                for (int rr = 0; rr < 4; ++rr) {
                    int row = rb * 16 + quad * 4 + rr;
                    int t = row >> 2, b = row & 3;
                    float val = (acc[c][rr] + bv) * 0.17677669529663687f;
                    qws[((size_t)((b * H + h) * T + t)) * HD + hd] = val;
                }
            } else if (sec == 1) {
                #pragma unroll
                for (int rr = 0; rr < 4; ++rr) {
                    int row = rb * 16 + quad * 4 + rr;
                    int s = row >> 2, b = row & 3;
                    int bh_ = b * 8 + h;
                    float val = acc[c][rr] + bv;
                    unsigned short hu = f2bf_u(val);
                    unsigned short lu = f2bf_u(val - bfu2f(hu));
                    size_t bi = ((size_t)bh_ * 768 + s) * 32 + hd;
                    KRh[bi] = hu;
                    KRl[bi] = lu;
                }
            } else {
                #pragma unroll
                for (int rr = 0; rr < 4; ++rr) {
                    int row = rb * 16 + quad * 4 + rr;
                    int s = row >> 2, b = row & 3;
                    int bh_ = b * 8 + h;
                    float val = acc[c][rr] + bv;
                    unsigned short hu = f2bf_u(val);
                    unsigned short lu = f2bf_u(val - bfu2f(hu));
                    int s16 = s >> 4, hp = (s >> 3) & 1, j = s & 7;
                    size_t bi = (((size_t)bh_ * 48 + s16) * 64 + hp * 32 + hd) * 8 + j;
                    VFh[bi] = hu;
                    VFl[bi] = lu;
                }
            }
        }
    } else if (bxx < 1024) {
        // ---- DT GEMM branch: DT_i[c][e] = sum_k ow_i[k][c] * Q_i[e][k] ----
        int unit = bxx - 576;
        int cgrp = unit & 3;          // 0..3
        int eb   = (unit >> 2) & 15;  // 0..15 (e block)
        int i    = unit >> 6;         // branch 0..6
        int w = threadIdx.x >> 6, lane = threadIdx.x & 63;
        int m = lane & 15, quad = lane >> 4;
        int cb = cgrp * 4 + w;        // c block 0..15

        f32x4 acc = {};
        #pragma unroll
        for (int kb = 0; kb < 8; ++kb) {
            // A: Q_i[e][k], e = eb*16+m (lane row), k = kb*32 + quad*8 + j
            float av[8];
            const float* qp = Qbuf + (size_t)i * 65536 +
                              (size_t)(eb * 16 + m) * 256 + kb * 32 + quad * 8;
            *(float4*)&av[0] = *(const float4*)qp;
            *(float4*)&av[4] = *(const float4*)(qp + 4);
            bf16x8 ah, al;
            f8_split(av, ah, al);
            // B: OWF fragments (col c, k elems) — unchanged layout
            const unsigned short* Bh = OWFh + (((size_t)(i * 16 + cb) * 8 + kb) * 64 + lane) * 8;
            const unsigned short* Bl = OWFl + (((size_t)(i * 16 + cb) * 8 + kb) * 64 + lane) * 8;
            bf16x8 bh = *(const bf16x8*)Bh;
            bf16x8 bl = *(const bf16x8*)Bl;
            MFMA3(acc, ah, al, bh, bl)
        }
        #pragma unroll
        for (int rr = 0; rr < 4; ++rr) {
            int e_ = eb * 16 + quad * 4 + rr;
            int c_ = cb * 16 + m;
            float a = acc[rr];
            unsigned short hu = f2bf_u(a);
            size_t fidx = (((size_t)(e_ >> 4) * 56 + i * 8 + (c_ >> 5)) * 64
                           + (e_ & 15) + (((c_ >> 3) & 3) << 4)) * 8 + (c_ & 7);
            DThi[fidx] = hu;
            DTlo[fidx] = f2bf_u(a - bfu2f(hu));
        }
    } else {
        // ---- bias2 branch ----
        int f32 = detect_f32(query);
        int e = bxx - 1024, r = threadIdx.x;
        red[r] = c0[r] * ldu(finalw, (size_t)e * 256 + r, f32);
        __syncthreads();
        for (int s = 128; s > 0; s >>= 1) {
            if (r < s) red[r] += red[r + s];
            __syncthreads();
        }
        if (r == 0)
            d0[e] = red[0] + ldu(finalb, e, f32);
    }
}

// ---------------------------------------------------------------------------
// STAGE 3 (round-28): attention ONLY (768 blocks, XCD-swizzled). wcomb2 moved
// to stage2 via the Q-associativity refactor. Dead-branch O stores skipped
// (live || mixed guard; mixed = stage4 boundary row-blocks t>>4 in {18,34}).
// ---------------------------------------------------------------------------
__global__ __launch_bounds__(256, 2) void stage3_kernel(
    const float* __restrict__ qws,
    const unsigned short* __restrict__ KRh, const unsigned short* __restrict__ KRl,
    const unsigned short* __restrict__ VFh, const unsigned short* __restrict__ VFl,
    unsigned short* __restrict__ Ohi, unsigned short* __restrict__ Olo)
{
    __shared__ __align__(16) float SMEM[7104];
    int tid = threadIdx.x;

    float (*AC2)[3][32][36] = (float(*)[3][32][36])&SMEM[0];      // 6912 f
    float (*SS2)[3][32]     = (float(*)[3][32])&SMEM[6912];       //  192 f
    int bid = blockIdx.x;
    int xcd = bid & 7, rr_ = bid >> 3;
    int j_ = rr_ / 24, tile = rr_ % 24;
    int bh = j_ * 8 + xcd;       // all 24 tiles of bh on one XCD
    int t0 = tile * 32;
    int w = tid >> 6, lane = tid & 63;
    int ln = lane & 31, h = lane >> 5;

    bf16x8 qbh[2], qbl[2];
    {
        const float* qr = qws + ((size_t)bh * T + t0 + ln) * HD + h * 8;
        #pragma unroll
        for (int c = 0; c < 2; ++c) {
            float qv[8];
            *(float4*)&qv[0] = *(const float4*)(qr + c * 16);
            *(float4*)&qv[4] = *(const float4*)(qr + c * 16 + 4);
            f8_split(qv, qbh[c], qbl[c]);
        }
    }

    f32x16 accA = {}, accB = {};
    float ssA = 0.f, ssB = 0.f;

    for (int q = 0; q < 3; ++q) {
        int ch = w * 3 + q;            // wave-contiguous chunks
        int sbase = ch * 64;
        int route = (ch == 5) ? 1 : (ch == 4 || ch == 8) ? 2 : 0;
        int bnd = (ch == 4) ? 300 : 550;
        bool c12 = (ch == 4);          // boundary cut 12 (else 6)

        // --- hoisted loads: all K and V fragments for this chunk ---
        bf16x8 kf0h[2], kf0l[2], kf1h[2], kf1l[2], vh[4], vl[4];
        #pragma unroll
        for (int st = 0; st < 2; ++st) {
            size_t krow = ((size_t)bh * 768 + sbase + st * 32 + ln) * 32 + h * 8;
            kf0h[st] = *(const bf16x8*)(KRh + krow);
            kf0l[st] = *(const bf16x8*)(KRl + krow);
            kf1h[st] = *(const bf16x8*)(KRh + krow + 16);
            kf1l[st] = *(const bf16x8*)(KRl + krow + 16);
        }
        #pragma unroll
        for (int ks = 0; ks < 4; ++ks) {
            size_t vidx = (((size_t)bh * 48 + ch * 4 + ks) * 64 + lane) * 8;
            vh[ks] = *(const bf16x8*)(VFh + vidx);
            vl[ks] = *(const bf16x8*)(VFl + vidx);
        }

        #pragma unroll
        for (int st = 0; st < 2; ++st) {
            f32x16 d = {};
            MFMA3W(d, kf0h[st], kf0l[st], qbh[0], qbl[0])
            MFMA3W(d, kf1h[st], kf1l[st], qbh[1], qbl[1])

            // pairwise exp + trunc-split + pack (PH/PL[8] only)
            int PH[8], PL[8];
            #pragma unroll
            for (int p = 0; p < 8; ++p) {
                float e0 = __expf(d[2 * p]);
                float e1 = __expf(d[2 * p + 1]);
                if (route == 2) {
                    int r0 = 2 * p;
                    int s0 = sbase + st * 32 + (r0 & 3) + 8 * (r0 >> 2) + 4 * h;
                    if (s0 < bnd) ssA += e0; else ssB += e0;
                    if (s0 + 1 < bnd) ssA += e1; else ssB += e1;
                } else if (route == 1) { ssB += e0 + e1; }
                else { ssA += e0 + e1; }
                unsigned b0 = __float_as_uint(e0), b1 = __float_as_uint(e1);
                float l0 = e0 - __uint_as_float(b0 & 0xffff0000u);
                float l1 = e1 - __uint_as_float(b1 & 0xffff0000u);
                PH[p] = (int)((b0 >> 16) | (b1 & 0xffff0000u));
                PL[p] = (int)((__float_as_uint(l0) >> 16) |
                              (__float_as_uint(l1) & 0xffff0000u));
            }

            #pragma unroll
            for (int ksl = 0; ksl < 2; ++ksl) {
                int ks = st * 2 + ksl;
                int cc = 4 * ksl;
                bf16x8 vbh = vh[ks];
                bf16x8 vbl = vl[ks];

                int sh0 = __shfl_xor(PH[cc+0], 32);
                int sh1 = __shfl_xor(PH[cc+1], 32);
                int sh2 = __shfl_xor(PH[cc+2], 32);
                int sh3 = __shfl_xor(PH[cc+3], 32);
                int sl0 = __shfl_xor(PL[cc+0], 32);
                int sl1 = __shfl_xor(PL[cc+1], 32);
                int sl2 = __shfl_xor(PL[cc+2], 32);
                int sl3 = __shfl_xor(PL[cc+3], 32);
                int FH0 = h ? sh2 : PH[cc+0];
                int FH1 = h ? sh3 : PH[cc+1];
                int FH2 = h ? PH[cc+2] : sh0;
                int FH3 = h ? PH[cc+3] : sh1;
                int FL0 = h ? sl2 : PL[cc+0];
                int FL1 = h ? sl3 : PL[cc+1];
                int FL2 = h ? PL[cc+2] : sl0;
                int FL3 = h ? PL[cc+3] : sl1;
                bf16x8 feh = mk8(FH0, FH1, FH2, FH3);
                bf16x8 fel = mk8(FL0, FL1, FL2, FL3);

                if (route == 0)      { MFMA3W(accA, feh, fel, vbh, vbl) }
                else if (route == 1) { MFMA3W(accB, feh, fel, vbh, vbl) }
                else {
                    if (ks < 2)       { MFMA3W(accA, feh, fel, vbh, vbl) }
                    else if (ks == 3) { MFMA3W(accB, feh, fel, vbh, vbl) }
                    else {
                        // word k: pass(A) iff 8h+2k+1 < cut (cut = 12 or 6)
                        int a0 = h ? (c12 ? FH0 : 0) : FH0;
                        int a1 = h ? (c12 ? FH1 : 0) : FH1;
                        int a2 = h ? 0 : FH2;
                        int a3 = h ? 0 : (c12 ? FH3 : 0);
                        int b0 = h ? (c12 ? 0 : FH0) : 0;
                        int b1 = h ? (c12 ? 0 : FH1) : 0;
                        int b2 = h ? FH2 : 0;
                        int b3 = h ? FH3 : (c12 ? 0 : FH3);
                        int la0 = h ? (c12 ? FL0 : 0) : FL0;
                        int la1 = h ? (c12 ? FL1 : 0) : FL1;
                        int la2 = h ? 0 : FL2;
                        int la3 = h ? 0 : (c12 ? FL3 : 0);
                        int lb0 = h ? (c12 ? 0 : FL0) : 0;
                        int lb1 = h ? (c12 ? 0 : FL1) : 0;
                        int lb2 = h ? FL2 : 0;
                        int lb3 = h ? FL3 : (c12 ? 0 : FL3);
                        bf16x8 fha = mk8(a0, a1, a2, a3), fla = mk8(la0, la1, la2, la3);
                        bf16x8 fhb = mk8(b0, b1, b2, b3), flb = mk8(lb0, lb1, lb2, lb3);
                        MFMA3W(accA, fha, fla, vbh, vbl)
                        MFMA3W(accB, fhb, flb, vbh, vbl)
                    }
                }
            }
        }
    }

    ssA += __shfl_xor(ssA, 32);
    ssB += __shfl_xor(ssB, 32);

    // wave -> segment: w0: A->0 | w1: A->0,B->1 | w2: A->1,B->2 | w3: A->2
    int bsel = w & 1;
    f32x16 zz = {};
    f32x16 o0 = (w <= 1) ? accA : zz;
    f32x16 o1 = (w == 1) ? accB : (w == 2) ? accA : zz;
    f32x16 o2 = (w == 2) ? accB : (w == 3) ? accA : zz;
    float s0 = (w <= 1) ? ssA : 0.f;
    float s1 = (w == 1) ? ssB : (w == 2) ? ssA : 0.f;
    float s2 = (w == 2) ? ssB : (w == 3) ? ssA : 0.f;

    if (w < 2) {
        #pragma unroll
        for (int r = 0; r < 16; ++r) {
            int t = (r & 3) + 8 * (r >> 2) + 4 * h;
            AC2[bsel][0][t][ln] = o0[r];
            AC2[bsel][1][t][ln] = o1[r];
            AC2[bsel][2][t][ln] = o2[r];
        }
        if (h == 0) {
            SS2[bsel][0][ln] = s0;
            SS2[bsel][1][ln] = s1;
            SS2[bsel][2][ln] = s2;
        }
    }
    __syncthreads();
    if (w >= 2) {
        #pragma unroll
        for (int r = 0; r < 16; ++r) {
            int t = (r & 3) + 8 * (r >> 2) + 4 * h;
            AC2[bsel][1][t][ln] += o1[r];
            AC2[bsel][2][t][ln] += o2[r];
        }
        if (h == 0) {
            SS2[bsel][1][ln] += s1;
            SS2[bsel][2][ln] += s2;
        }
    }
    __syncthreads();

    // epilogue: combine bufs, normalize, 7-branch fragment-major O store
    // (B-MAJOR rows; dead-i stores skipped unless boundary-mixed block)
    int tt = tid >> 3, q4 = tid & 7;
    float Pv[3][4], S[3];
    #pragma unroll
    for (int sg = 0; sg < 3; ++sg) {
        const float4 a = *(const float4*)&AC2[0][sg][tt][q4 * 4];
        const float4 b = *(const float4*)&AC2[1][sg][tt][q4 * 4];
        Pv[sg][0] = a.x + b.x; Pv[sg][1] = a.y + b.y;
        Pv[sg][2] = a.z + b.z; Pv[sg][3] = a.w + b.w;
        S[sg] = SS2[0][sg][tt] + SS2[1][sg][tt];
    }

    int t_glob = t0 + tt;
    int g = (t_glob < 300) ? 0 : (t_glob < 550 ? 1 : 2);
    int mixed = (((t_glob >> 4) == 18) || ((t_glob >> 4) == 34)) ? 1 : 0;
    int b_ = bh >> 3, h_ = bh & 7;
    int row = b_ * T + t_glob;          // B-MAJOR row
    int lslot = (row & 15) + ((q4 >> 1) << 4);
    int j0 = (q4 & 1) * 4;
    size_t fbase = (((size_t)(row >> 4) * 56 + h_) * 64 + lslot) * 8 + j0;
    const int masks[7] = {7, 3, 5, 6, 1, 2, 4};
    #pragma unroll
    for (int i = 0; i < 7; ++i) {
        int mm = masks[i];
        int live = (mm >> g) & 1;
        if (!(live | mixed)) continue;      // dead, never read by stage4
        float n0 = 0.f, n1 = 0.f, n2 = 0.f, n3 = 0.f, den = 0.f;
        if (mm & 1) { n0 += Pv[0][0]; n1 += Pv[0][1]; n2 += Pv[0][2]; n3 += Pv[0][3]; den += S[0]; }
        if (mm & 2) { n0 += Pv[1][0]; n1 += Pv[1][1]; n2 += Pv[1][2]; n3 += Pv[1][3]; den += S[1]; }
        if (mm & 4) { n0 += Pv[2][0]; n1 += Pv[2][1]; n2 += Pv[2][2]; n3 += Pv[2][3]; den += S[2]; }
        float r = 1.f / den;
        float o[4];
        o[0] = live ? n0 * r : 0.f;
        o[1] = live ? n1 * r : 0.f;
        o[2] = live ? n2 * r : 0.f;
        o[3] = live ? n3 * r : 0.f;
        ushort4 hi4, lo4;
        unsigned short* hp = (unsigned short*)&hi4;
        unsigned short* lp = (unsigned short*)&lo4;
        #pragma unroll
        for (int jq = 0; jq < 4; ++jq) {
            unsigned short hu = f2bf_u(o[jq]);
            hp[jq] = hu;
            lp[jq] = f2bf_u(o[jq] - bfu2f(hu));
        }
        size_t addr = fbase + (size_t)i * (8 * 64 * 8);
        *(ushort4*)&Ohi[addr] = hi4;
        *(ushort4*)&Olo[addr] = lo4;
    }
}

// ---------------------------------------------------------------------------
// STAGE 4 (round-26, unchanged): result = O@Dstack + d0, B-MAJOR O rows,
// XCD-swizzled 1D grid.
// ---------------------------------------------------------------------------
__global__ __launch_bounds__(256) void final_gemm_mfma_kernel(
    const unsigned short* __restrict__ Ohi, const unsigned short* __restrict__ Olo,
    const unsigned short* __restrict__ DThi, const unsigned short* __restrict__ DTlo,
    const float* __restrict__ d0, const void* query,
    void* __restrict__ outv)
{
    int f32 = detect_f32(query);
    int bid = blockIdx.x;                 // 0..767
    int xcd = bid & 7, rr_ = bid >> 3;    // rr_ ∈ [0,96)
    int slot = rr_ >> 2, bx = rr_ & 3;    // slot ∈ [0,24)
    int by = slot * 8 + xcd;              // by ∈ [0,192), bijective
    int w  = threadIdx.x >> 6;
    int lane = threadIdx.x & 63;
    int m = lane & 15, quad = lane >> 4;
    int R0 = by * 16, C0 = bx * 64 + w * 16;

    // B-major rows: b = R0/768, t range [R0%768, R0%768+15] (16 | 768)
    int b_out = R0 / 768;
    int tfirst = R0 - b_out * 768;
    int g0 = (tfirst < 300) ? 0 : (tfirst < 550 ? 1 : 2);
    int g1 = (tfirst + 15 < 300) ? 0 : (tfirst + 15 < 550 ? 1 : 2);
    int activeset = (1 << g0) | (1 << g1);
    const int masks[7] = {7, 3, 5, 6, 1, 2, 4};

    const unsigned short* Abase_h = Ohi + (size_t)by * 56 * 512 + lane * 8;
    const unsigned short* Abase_l = Olo + (size_t)by * 56 * 512 + lane * 8;
    const unsigned short* Bbase_h = DThi + (size_t)(bx * 4 + w) * 56 * 512 + lane * 8;
    const unsigned short* Bbase_l = DTlo + (size_t)(bx * 4 + w) * 56 * 512 + lane * 8;

    f32x4 acc = {};
    for (int i = 0; i < 7; ++i) {
        if (!(masks[i] & activeset)) continue;
        #pragma unroll
        for (int kb = 0; kb < 8; ++kb) {
            size_t off = (size_t)(i * 8 + kb) * 512;
            bf16x8 ah = *(const bf16x8*)(Abase_h + off);
            bf16x8 al = *(const bf16x8*)(Abase_l + off);
            bf16x8 bh = *(const bf16x8*)(Bbase_h + off);
            bf16x8 bl = *(const bf16x8*)(Bbase_l + off);
            acc = __builtin_amdgcn_mfma_f32_16x16x32_bf16(ah, bh, acc, 0, 0, 0);
            acc = __builtin_amdgcn_mfma_f32_16x16x32_bf16(ah, bl, acc, 0, 0, 0);
            acc = __builtin_amdgcn_mfma_f32_16x16x32_bf16(al, bh, acc, 0, 0, 0);
        }
    }
    float dv = d0[C0 + m];
    #pragma unroll
    for (int r = 0; r < 4; ++r) {
        int t = tfirst + quad * 4 + r;
        int col = C0 + m;
        float val = acc[r] + dv;
        size_t orow = (size_t)t * B + b_out;        // back to (t,b) row order
        if (f32) ((float*)outv)[orow * 256 + col] = val;
        else ((__hip_bfloat16*)outv)[orow * 256 + col] = __float2bfloat16(val);
    }
}

// ---------------------------------------------------------------------------
extern "C" void kernel_launch(void* const* d_in, const int* in_sizes, int n_in,
                              void* d_out, int out_size, void* d_ws, size_t ws_size,
                              hipStream_t stream) {
    const void* query     = d_in[0];
    const void* key       = d_in[1];
    const void* value     = d_in[2];
    const void* in_proj_w = d_in[3];
    const void* in_proj_b = d_in[4];
    const void* out_w     = d_in[5];
    const void* out_b     = d_in[6];
    const void* s_l_w     = d_in[7];
    const void* s_l_b     = d_in[8];
    const void* s_a_w     = d_in[9];
    const void* s_a_b     = d_in[10];
    const void* s_v_w     = d_in[11];
    const void* s_v_b     = d_in[12];
    const void* final_w   = d_in[13];
    const void* final_b   = d_in[14];

    float* ws     = (float*)d_ws;
    float* qws    = ws;                 //   786432 f (q fp32)
    unsigned short* KRh = (unsigned short*)(ws + 786432);   // K rows [bh][s][hd]
    unsigned short* KRl = KRh + 786432;
    unsigned short* VFh = (unsigned short*)(ws + 1572864);  // V frag-major
    unsigned short* VFl = VFh + 786432;
    // O region [2359296, 7864320): Ohi/Olo for attn+final; aliased by the
    // conversion buffers WF/OWF (consumed before attn writes O).
    unsigned short* Ohi = (unsigned short*)(ws + 2359296);   // 5505024 bf16
    unsigned short* Olo = (unsigned short*)(ws + 5111808);   // 5505024 bf16
    unsigned short* WFh = (unsigned short*)(ws + 2359296);   //  196608 bf16
    unsigned short* WFl = WFh + 196608;                      //  196608 bf16
    unsigned short* OWFh = (unsigned short*)(ws + 4915200);  //  458752 bf16
    unsigned short* OWFl = OWFh + 458752;                    // ends f 5374208
    float* Qbuf   = ws + 7864320;       //   458752 f  (Q_i = fw @ G_i)
    unsigned short* DThi = (unsigned short*)(ws + 8323072);  // 458752 bf16
    unsigned short* DTlo = (unsigned short*)(ws + 8552448);  // 458752 bf16
    float* d0     = ws + 8781824;       //      256 f
    float* c0     = ws + 8782336;       //      256 f

    stage1_kernel<<<1024, 256, 0, stream>>>(query, in_proj_w,
                                            s_l_w, s_a_w, s_v_w, out_w,
                                            out_b, s_l_b, s_a_b, s_v_b,
                                            final_w,
                                            WFh, WFl, OWFh, OWFl, Qbuf, c0);
    stage2_kernel<<<1280, 256, 0, stream>>>(query, key, value,
                                            WFh, WFl, in_proj_b, qws,
                                            KRh, KRl, VFh, VFl,
                                            OWFh, OWFl, Qbuf,
                                            DThi, DTlo,
                                            c0, final_w, final_b, d0);
    stage3_kernel<<<768, 256, 0, stream>>>(qws, KRh, KRl, VFh, VFl,
                                           Ohi, Olo);
    final_gemm_mfma_kernel<<<768, 256, 0, stream>>>(Ohi, Olo, DThi, DTlo,
                                                    d0, query, d_out);
}

// Round 11
// 158.976 us; speedup vs baseline: 1.0521x; 1.0521x over previous
//
#include <hip/hip_runtime.h>
#include <hip/hip_bf16.h>

#define E 256
#define H 8
#define HD 32
#define T 768
#define B 4
#define BH 32
// segments: L=[0,300), A=[300,550), V=[550,768)

typedef __attribute__((ext_vector_type(8))) short bf16x8;
typedef __attribute__((ext_vector_type(4))) float f32x4;
typedef __attribute__((ext_vector_type(16))) float f32x16;

__device__ __forceinline__ float b2f(__hip_bfloat16 x) { return __bfloat162float(x); }

__device__ __forceinline__ unsigned short f2bf_u(float x) {
    __hip_bfloat16 h = __float2bfloat16(x);
    return *(unsigned short*)&h;
}
__device__ __forceinline__ float bfu2f(unsigned short u) {
    return __uint_as_float(((unsigned int)u) << 16);
}

// Inline per-wave dtype detection: fp32 input read as bf16 -> garbage
// exponents in query[0..255]. 4 strided u16 loads/lane + __any. Wave-uniform.
__device__ __forceinline__ int detect_f32(const void* query) {
    const unsigned short* q = (const unsigned short*)query;
    int lane = threadIdx.x & 63;
    int bad = 0;
    #pragma unroll
    for (int i = 0; i < 4; ++i) {
        float v = bfu2f(q[lane + i * 64]);
        bad |= (!(v == v) || fabsf(v) > 1e4f) ? 1 : 0;
    }
    return __any(bad) ? 1 : 0;
}

// split fp32[8] -> bf16 hi + lo fragments (RTNE)
__device__ __forceinline__ void f8_split(const float* v, bf16x8& h, bf16x8& l) {
    #pragma unroll
    for (int e = 0; e < 8; ++e) {
        unsigned short hu = f2bf_u(v[e]);
        h[e] = (short)hu;
        l[e] = (short)f2bf_u(v[e] - bfu2f(hu));
    }
}

#define MFMA3(ACC, AH, AL, BH_, BL_)                                         \
    ACC = __builtin_amdgcn_mfma_f32_16x16x32_bf16(AH, BH_, ACC, 0, 0, 0);    \
    ACC = __builtin_amdgcn_mfma_f32_16x16x32_bf16(AH, BL_, ACC, 0, 0, 0);    \
    ACC = __builtin_amdgcn_mfma_f32_16x16x32_bf16(AL, BH_, ACC, 0, 0, 0);

#define MFMA3W(ACC, AH, AL, BH_, BL_)                                        \
    ACC = __builtin_amdgcn_mfma_f32_32x32x16_bf16(AH, BH_, ACC, 0, 0, 0);    \
    ACC = __builtin_amdgcn_mfma_f32_32x32x16_bf16(AH, BL_, ACC, 0, 0, 0);    \
    ACC = __builtin_amdgcn_mfma_f32_32x32x16_bf16(AL, BH_, ACC, 0, 0, 0);

__device__ __forceinline__ bf16x8 mk8(int a, int b, int c, int d) {
    union { int i[4]; bf16x8 v; } u;
    u.i[0] = a; u.i[1] = b; u.i[2] = c; u.i[3] = d;
    return u.v;
}

// dtype-agnostic scalar load: f32 ? float : bf16
__device__ __forceinline__ float ldu(const void* p, size_t i, int f32) {
    if (f32) return ((const float*)p)[i];
    return b2f(((const __hip_bfloat16*)p)[i]);
}

// G_i row loader (branch-summed s_*_w blocks)
__device__ __forceinline__ float gsum_load(int i, int r2, int r,
                                           const void* sl, const void* sa,
                                           const void* sv, int f32)
{
    size_t base = (size_t)r2 * 1024;
    switch (i) {
        case 0: return ldu(sl, base + r, f32) + ldu(sa, base + r, f32) + ldu(sv, base + r, f32);
        case 1: return ldu(sl, base + 256 + r, f32) + ldu(sa, base + 256 + r, f32);
        case 2: return ldu(sl, base + 512 + r, f32) + ldu(sv, base + 256 + r, f32);
        case 3: return ldu(sa, base + 512 + r, f32) + ldu(sv, base + 512 + r, f32);
        case 4: return ldu(sl, base + 768 + r, f32);
        case 5: return ldu(sa, base + 768 + r, f32);
        default: return ldu(sv, base + 768 + r, f32);
    }
}

// ---------------------------------------------------------------------------
// STAGE 1 (round-27 proven): W/G/OWF conversion (0..543) + bias1 (544..799).
// ---------------------------------------------------------------------------
__global__ __launch_bounds__(256) void stage1_kernel(
    const void* query, const void* w,
    const void* sl, const void* sa, const void* sv, const void* outw,
    const void* outb, const void* slb, const void* sab, const void* svb,
    unsigned short* __restrict__ WFh, unsigned short* __restrict__ WFl,
    unsigned short* __restrict__ GFh, unsigned short* __restrict__ GFl,
    unsigned short* __restrict__ OWFh, unsigned short* __restrict__ OWFl,
    float* __restrict__ c0)
{
    __shared__ float red[256];
    int f32 = detect_f32(query);
    if (blockIdx.x < 544) {
        // ---- conversion branch ----
        int item = blockIdx.x * 256 + threadIdx.x;
        if (item < 24576) {                        // W: 768 rows x 32 kg
            int gc = item >> 5, kg = item & 31;
            float v[8];
            if (f32) {
                const float4* p = (const float4*)((const float*)w +
                                   (size_t)gc * 256 + kg * 8);
                *(float4*)&v[0] = p[0];
                *(float4*)&v[4] = p[1];
            } else {
                #pragma unroll
                for (int j = 0; j < 8; ++j)
                    v[j] = ldu(w, (size_t)gc * 256 + kg * 8 + j, 0);
            }
            bf16x8 h, l;
            f8_split(v, h, l);
            int sec = gc >> 8, c = gc & 255;
            int cb = c >> 4, kb = kg >> 2;
            int lane = (c & 15) | ((kg & 3) << 4);
            size_t idx = (((size_t)(sec * 16 + cb) * 8 + kb) * 64 + lane) * 8;
            *(bf16x8*)&WFh[idx] = h;
            *(bf16x8*)&WFl[idx] = l;
        } else if (item < 81920) {                 // G: 7 x 256 r2 x 32 kg
            int rem = item - 24576;
            int i = rem >> 13;
            int rest = rem & 8191;
            int r2 = rest >> 5, kg = rest & 31;
            float v[8];
            #pragma unroll
            for (int j = 0; j < 8; ++j)
                v[j] = gsum_load(i, r2, kg * 8 + j, sl, sa, sv, f32);
            bf16x8 h, l;
            f8_split(v, h, l);
            int rb = r2 >> 4, kb = kg >> 2;
            int lane = (r2 & 15) | ((kg & 3) << 4);
            size_t idx = (((size_t)(i * 16 + rb) * 8 + kb) * 64 + lane) * 8;
            *(bf16x8*)&GFh[idx] = h;
            *(bf16x8*)&GFl[idx] = l;
        } else if (item < 139264) {                // OW^T: 7 x 32 kg x 256 c
            int rem = item - 81920;
            int i = rem >> 13;
            int rest = rem & 8191;
            int kg = rest >> 8, c = rest & 255;
            float v[8];
            #pragma unroll
            for (int j = 0; j < 8; ++j)
                v[j] = ldu(outw, (size_t)i * 65536 + (kg * 8 + j) * 256 + c, f32);
            bf16x8 h, l;
            f8_split(v, h, l);
            int cb = c >> 4, kb = kg >> 2;
            int lane = (c & 15) | ((kg & 3) << 4);
            size_t idx = (((size_t)(i * 16 + cb) * 8 + kb) * 64 + lane) * 8;
            *(bf16x8*)&OWFh[idx] = h;
            *(bf16x8*)&OWFl[idx] = l;
        }
    } else {
        // ---- bias1 branch ----
        int r2 = blockIdx.x - 544, m = threadIdx.x;
        float acc = 0.f;
        #pragma unroll
        for (int i = 0; i < 7; ++i)
            acc += ldu(outb, i * 256 + m, f32) * gsum_load(i, r2, m, sl, sa, sv, f32);
        red[m] = acc;
        __syncthreads();
        for (int s = 128; s > 0; s >>= 1) {
            if (m < s) red[m] += red[m + s];
            __syncthreads();
        }
        if (m == 0)
            c0[r2] = red[0] + ldu(slb, r2, f32) + ldu(sab, r2, f32) + ldu(svb, r2, f32);
    }
}

// ---------------------------------------------------------------------------
// STAGE 2 (round-27 proven): qkv direct-X (0..575) + wcomb1 (576..1023)
// + bias2 (1024..1279).
// ---------------------------------------------------------------------------
__global__ __launch_bounds__(256) void stage2_kernel(
    const void* query, const void* key, const void* value,
    const unsigned short* __restrict__ WFh, const unsigned short* __restrict__ WFl,
    const void* bias,
    float* __restrict__ qws,
    unsigned short* __restrict__ KRh, unsigned short* __restrict__ KRl,
    unsigned short* __restrict__ VFh, unsigned short* __restrict__ VFl,
    const unsigned short* __restrict__ GFh, const unsigned short* __restrict__ GFl,
    const unsigned short* __restrict__ OWFh, const unsigned short* __restrict__ OWFl,
    float* __restrict__ Mtmp,
    const float* __restrict__ c0, const void* finalw, const void* finalb,
    float* __restrict__ d0)
{
    __shared__ float red[256];
    int bxx = blockIdx.x;
    if (bxx < 576) {
        // ---- qkv branch (direct-X, full row-strip per block) ----
        int f32 = detect_f32(query);
        int sec = bxx / 192;          // 0..2
        int rb  = bxx % 192;          // 0..191 rowblk
        const void* X = (sec == 0) ? query : (sec == 1) ? key : value;
        int w = threadIdx.x >> 6, lane = threadIdx.x & 63;
        int m = lane & 15, quad = lane >> 4;

        size_t aoff0 = (size_t)(rb * 16 + (lane & 15)) * 256 + quad * 8;

        f32x4 acc[4] = {};
        #pragma unroll
        for (int kb = 0; kb < 8; ++kb) {
            float av[8];
            size_t aoff = aoff0 + kb * 32;
            if (f32) {
                const float4* p = (const float4*)((const float*)X + aoff);
                *(float4*)&av[0] = p[0];
                *(float4*)&av[4] = p[1];
            } else {
                #pragma unroll
                for (int j = 0; j < 8; ++j)
                    av[j] = ldu(X, aoff + j, 0);
            }
            bf16x8 ah, al;
            f8_split(av, ah, al);
            #pragma unroll
            for (int c = 0; c < 4; ++c) {
                int cb = w * 4 + c;
                const unsigned short* Bh = WFh + (((size_t)(sec * 16 + cb) * 8 + kb) * 64 + lane) * 8;
                const unsigned short* Bl = WFl + (((size_t)(sec * 16 + cb) * 8 + kb) * 64 + lane) * 8;
                bf16x8 bh = *(const bf16x8*)Bh;
                bf16x8 bl = *(const bf16x8*)Bl;
                MFMA3(acc[c], ah, al, bh, bl)
            }
        }

        #pragma unroll
        for (int c = 0; c < 4; ++c) {
            int cb = w * 4 + c;
            int c_local = cb * 16 + m;             // col within section
            float bv = ldu(bias, sec * 256 + c_local, f32);
            int h = c_local >> 5, hd = c_local & 31;

            if (sec == 0) {
                #pragma unroll
                for (int rr = 0; rr < 4; ++rr) {
                    int row = rb * 16 + quad * 4 + rr;
                    int t = row >> 2, b = row & 3;
                    float val = (acc[c][rr] + bv) * 0.17677669529663687f;
                    qws[((size_t)((b * H + h) * T + t)) * HD + hd] = val;
                }
            } else if (sec == 1) {
                #pragma unroll
                for (int rr = 0; rr < 4; ++rr) {
                    int row = rb * 16 + quad * 4 + rr;
                    int s = row >> 2, b = row & 3;
                    int bh_ = b * 8 + h;
                    float val = acc[c][rr] + bv;
                    unsigned short hu = f2bf_u(val);
                    unsigned short lu = f2bf_u(val - bfu2f(hu));
                    size_t bi = ((size_t)bh_ * 768 + s) * 32 + hd;
                    KRh[bi] = hu;
                    KRl[bi] = lu;
                }
            } else {
                #pragma unroll
                for (int rr = 0; rr < 4; ++rr) {
                    int row = rb * 16 + quad * 4 + rr;
                    int s = row >> 2, b = row & 3;
                    int bh_ = b * 8 + h;
                    float val = acc[c][rr] + bv;
                    unsigned short hu = f2bf_u(val);
                    unsigned short lu = f2bf_u(val - bfu2f(hu));
                    int s16 = s >> 4, hp = (s >> 3) & 1, j = s & 7;
                    size_t bi = (((size_t)bh_ * 48 + s16) * 64 + hp * 32 + hd) * 8 + j;
                    VFh[bi] = hu;
                    VFl[bi] = lu;
                }
            }
        }
    } else if (bxx < 1024) {
        // ---- wcomb1 branch ----
        int idx = bxx - 576;
        int cgrp = idx & 3;           // 0..3
        int rb   = (idx >> 2) & 15;   // 0..15
        int i    = idx >> 6;          // 0..6
        int w = threadIdx.x >> 6, lane = threadIdx.x & 63;
        int m = lane & 15, quad = lane >> 4;
        int cb = cgrp * 4 + w;        // c block 0..15

        const unsigned short* Ah = GFh + (((size_t)(i * 16 + rb) * 8) * 64 + lane) * 8;
        const unsigned short* Al = GFl + (((size_t)(i * 16 + rb) * 8) * 64 + lane) * 8;
        const unsigned short* Bh = OWFh + (((size_t)(i * 16 + cb) * 8) * 64 + lane) * 8;
        const unsigned short* Bl = OWFl + (((size_t)(i * 16 + cb) * 8) * 64 + lane) * 8;

        f32x4 acc = {};
        #pragma unroll
        for (int kb = 0; kb < 8; ++kb) {
            size_t off = (size_t)kb * 512;
            bf16x8 ah = *(const bf16x8*)(Ah + off);
            bf16x8 al = *(const bf16x8*)(Al + off);
            bf16x8 bh = *(const bf16x8*)(Bh + off);
            bf16x8 bl = *(const bf16x8*)(Bl + off);
            MFMA3(acc, ah, al, bh, bl)
        }
        #pragma unroll
        for (int rr = 0; rr < 4; ++rr) {
            int r2 = rb * 16 + quad * 4 + rr;
            Mtmp[(size_t)i * 65536 + r2 * 256 + cb * 16 + m] = acc[rr];
        }
    } else {
        // ---- bias2 branch ----
        int f32 = detect_f32(query);
        int e = bxx - 1024, r = threadIdx.x;
        red[r] = c0[r] * ldu(finalw, (size_t)e * 256 + r, f32);
        __syncthreads();
        for (int s = 128; s > 0; s >>= 1) {
            if (r < s) red[r] += red[r + s];
            __syncthreads();
        }
        if (r == 0)
            d0[e] = red[0] + ldu(finalb, e, f32);
    }
}

// ---------------------------------------------------------------------------
// STAGE 3 (round-29): attn (0..767, XCD-swizzled) + wcomb2 (768..1215).
// NEW vs round-27: dead-branch O-store skip in the attn epilogue
// (live || mixed guard; mixed = stage4 boundary row-blocks t>>4 in {18,34};
// validated correct by the round-10 pass).
// ---------------------------------------------------------------------------
__global__ __launch_bounds__(256, 2) void stage3_kernel(
    const float* __restrict__ qws,
    const unsigned short* __restrict__ KRh, const unsigned short* __restrict__ KRl,
    const unsigned short* __restrict__ VFh, const unsigned short* __restrict__ VFl,
    unsigned short* __restrict__ Ohi, unsigned short* __restrict__ Olo,
    const float* __restrict__ Mtmp, const void* finalw, const void* query,
    unsigned short* __restrict__ DThi, unsigned short* __restrict__ DTlo)
{
    __shared__ __align__(16) float SMEM[7104];
    int tid = threadIdx.x;

    if (blockIdx.x < 768) {
        // ---- attn branch (barrier-free 32x32 MFMA, XCD-swizzled) ----
        float (*AC2)[3][32][36] = (float(*)[3][32][36])&SMEM[0];      // 6912 f
        float (*SS2)[3][32]     = (float(*)[3][32])&SMEM[6912];       //  192 f
        int bid = blockIdx.x;
        int xcd = bid & 7, rr_ = bid >> 3;
        int j_ = rr_ / 24, tile = rr_ % 24;
        int bh = j_ * 8 + xcd;       // all 24 tiles of bh on one XCD
        int t0 = tile * 32;
        int w = tid >> 6, lane = tid & 63;
        int ln = lane & 31, h = lane >> 5;

        bf16x8 qbh[2], qbl[2];
        {
            const float* qr = qws + ((size_t)bh * T + t0 + ln) * HD + h * 8;
            #pragma unroll
            for (int c = 0; c < 2; ++c) {
                float qv[8];
                *(float4*)&qv[0] = *(const float4*)(qr + c * 16);
                *(float4*)&qv[4] = *(const float4*)(qr + c * 16 + 4);
                f8_split(qv, qbh[c], qbl[c]);
            }
        }

        f32x16 accA = {}, accB = {};
        float ssA = 0.f, ssB = 0.f;

        for (int q = 0; q < 3; ++q) {
            int ch = w * 3 + q;            // wave-contiguous chunks
            int sbase = ch * 64;
            int route = (ch == 5) ? 1 : (ch == 4 || ch == 8) ? 2 : 0;
            int bnd = (ch == 4) ? 300 : 550;
            bool c12 = (ch == 4);          // boundary cut 12 (else 6)

            // --- hoisted loads: all K and V fragments for this chunk ---
            bf16x8 kf0h[2], kf0l[2], kf1h[2], kf1l[2], vh[4], vl[4];
            #pragma unroll
            for (int st = 0; st < 2; ++st) {
                size_t krow = ((size_t)bh * 768 + sbase + st * 32 + ln) * 32 + h * 8;
                kf0h[st] = *(const bf16x8*)(KRh + krow);
                kf0l[st] = *(const bf16x8*)(KRl + krow);
                kf1h[st] = *(const bf16x8*)(KRh + krow + 16);
                kf1l[st] = *(const bf16x8*)(KRl + krow + 16);
            }
            #pragma unroll
            for (int ks = 0; ks < 4; ++ks) {
                size_t vidx = (((size_t)bh * 48 + ch * 4 + ks) * 64 + lane) * 8;
                vh[ks] = *(const bf16x8*)(VFh + vidx);
                vl[ks] = *(const bf16x8*)(VFl + vidx);
            }

            #pragma unroll
            for (int st = 0; st < 2; ++st) {
                f32x16 d = {};
                MFMA3W(d, kf0h[st], kf0l[st], qbh[0], qbl[0])
                MFMA3W(d, kf1h[st], kf1l[st], qbh[1], qbl[1])

                // pairwise exp + trunc-split + pack (PH/PL[8] only)
                int PH[8], PL[8];
                #pragma unroll
                for (int p = 0; p < 8; ++p) {
                    float e0 = __expf(d[2 * p]);
                    float e1 = __expf(d[2 * p + 1]);
                    if (route == 2) {
                        int r0 = 2 * p;
                        int s0 = sbase + st * 32 + (r0 & 3) + 8 * (r0 >> 2) + 4 * h;
                        if (s0 < bnd) ssA += e0; else ssB += e0;
                        if (s0 + 1 < bnd) ssA += e1; else ssB += e1;
                    } else if (route == 1) { ssB += e0 + e1; }
                    else { ssA += e0 + e1; }
                    unsigned b0 = __float_as_uint(e0), b1 = __float_as_uint(e1);
                    float l0 = e0 - __uint_as_float(b0 & 0xffff0000u);
                    float l1 = e1 - __uint_as_float(b1 & 0xffff0000u);
                    PH[p] = (int)((b0 >> 16) | (b1 & 0xffff0000u));
                    PL[p] = (int)((__float_as_uint(l0) >> 16) |
                                  (__float_as_uint(l1) & 0xffff0000u));
                }

                #pragma unroll
                for (int ksl = 0; ksl < 2; ++ksl) {
                    int ks = st * 2 + ksl;
                    int cc = 4 * ksl;
                    bf16x8 vbh = vh[ks];
                    bf16x8 vbl = vl[ks];

                    int sh0 = __shfl_xor(PH[cc+0], 32);
                    int sh1 = __shfl_xor(PH[cc+1], 32);
                    int sh2 = __shfl_xor(PH[cc+2], 32);
                    int sh3 = __shfl_xor(PH[cc+3], 32);
                    int sl0 = __shfl_xor(PL[cc+0], 32);
                    int sl1 = __shfl_xor(PL[cc+1], 32);
                    int sl2 = __shfl_xor(PL[cc+2], 32);
                    int sl3 = __shfl_xor(PL[cc+3], 32);
                    int FH0 = h ? sh2 : PH[cc+0];
                    int FH1 = h ? sh3 : PH[cc+1];
                    int FH2 = h ? PH[cc+2] : sh0;
                    int FH3 = h ? PH[cc+3] : sh1;
                    int FL0 = h ? sl2 : PL[cc+0];
                    int FL1 = h ? sl3 : PL[cc+1];
                    int FL2 = h ? PL[cc+2] : sl0;
                    int FL3 = h ? PL[cc+3] : sl1;
                    bf16x8 feh = mk8(FH0, FH1, FH2, FH3);
                    bf16x8 fel = mk8(FL0, FL1, FL2, FL3);

                    if (route == 0)      { MFMA3W(accA, feh, fel, vbh, vbl) }
                    else if (route == 1) { MFMA3W(accB, feh, fel, vbh, vbl) }
                    else {
                        if (ks < 2)       { MFMA3W(accA, feh, fel, vbh, vbl) }
                        else if (ks == 3) { MFMA3W(accB, feh, fel, vbh, vbl) }
                        else {
                            // word k: pass(A) iff 8h+2k+1 < cut (cut = 12 or 6)
                            int a0 = h ? (c12 ? FH0 : 0) : FH0;
                            int a1 = h ? (c12 ? FH1 : 0) : FH1;
                            int a2 = h ? 0 : FH2;
                            int a3 = h ? 0 : (c12 ? FH3 : 0);
                            int b0 = h ? (c12 ? 0 : FH0) : 0;
                            int b1 = h ? (c12 ? 0 : FH1) : 0;
                            int b2 = h ? FH2 : 0;
                            int b3 = h ? FH3 : (c12 ? 0 : FH3);
                            int la0 = h ? (c12 ? FL0 : 0) : FL0;
                            int la1 = h ? (c12 ? FL1 : 0) : FL1;
                            int la2 = h ? 0 : FL2;
                            int la3 = h ? 0 : (c12 ? FL3 : 0);
                            int lb0 = h ? (c12 ? 0 : FL0) : 0;
                            int lb1 = h ? (c12 ? 0 : FL1) : 0;
                            int lb2 = h ? FL2 : 0;
                            int lb3 = h ? FL3 : (c12 ? 0 : FL3);
                            bf16x8 fha = mk8(a0, a1, a2, a3), fla = mk8(la0, la1, la2, la3);
                            bf16x8 fhb = mk8(b0, b1, b2, b3), flb = mk8(lb0, lb1, lb2, lb3);
                            MFMA3W(accA, fha, fla, vbh, vbl)
                            MFMA3W(accB, fhb, flb, vbh, vbl)
                        }
                    }
                }
            }
        }

        ssA += __shfl_xor(ssA, 32);
        ssB += __shfl_xor(ssB, 32);

        // wave -> segment: w0: A->0 | w1: A->0,B->1 | w2: A->1,B->2 | w3: A->2
        int bsel = w & 1;
        f32x16 zz = {};
        f32x16 o0 = (w <= 1) ? accA : zz;
        f32x16 o1 = (w == 1) ? accB : (w == 2) ? accA : zz;
        f32x16 o2 = (w == 2) ? accB : (w == 3) ? accA : zz;
        float s0 = (w <= 1) ? ssA : 0.f;
        float s1 = (w == 1) ? ssB : (w == 2) ? ssA : 0.f;
        float s2 = (w == 2) ? ssB : (w == 3) ? ssA : 0.f;

        if (w < 2) {
            #pragma unroll
            for (int r = 0; r < 16; ++r) {
                int t = (r & 3) + 8 * (r >> 2) + 4 * h;
                AC2[bsel][0][t][ln] = o0[r];
                AC2[bsel][1][t][ln] = o1[r];
                AC2[bsel][2][t][ln] = o2[r];
            }
            if (h == 0) {
                SS2[bsel][0][ln] = s0;
                SS2[bsel][1][ln] = s1;
                SS2[bsel][2][ln] = s2;
            }
        }
        __syncthreads();
        if (w >= 2) {
            #pragma unroll
            for (int r = 0; r < 16; ++r) {
                int t = (r & 3) + 8 * (r >> 2) + 4 * h;
                AC2[bsel][1][t][ln] += o1[r];
                AC2[bsel][2][t][ln] += o2[r];
            }
            if (h == 0) {
                SS2[bsel][1][ln] += s1;
                SS2[bsel][2][ln] += s2;
            }
        }
        __syncthreads();

        // epilogue: combine bufs, normalize, 7-branch fragment-major O store
        // (B-MAJOR rows; dead-i stores skipped unless boundary-mixed block)
        int tt = tid >> 3, q4 = tid & 7;
        float Pv[3][4], S[3];
        #pragma unroll
        for (int sg = 0; sg < 3; ++sg) {
            const float4 a = *(const float4*)&AC2[0][sg][tt][q4 * 4];
            const float4 b = *(const float4*)&AC2[1][sg][tt][q4 * 4];
            Pv[sg][0] = a.x + b.x; Pv[sg][1] = a.y + b.y;
            Pv[sg][2] = a.z + b.z; Pv[sg][3] = a.w + b.w;
            S[sg] = SS2[0][sg][tt] + SS2[1][sg][tt];
        }

        int t_glob = t0 + tt;
        int g = (t_glob < 300) ? 0 : (t_glob < 550 ? 1 : 2);
        int mixed = (((t_glob >> 4) == 18) || ((t_glob >> 4) == 34)) ? 1 : 0;
        int b_ = bh >> 3, h_ = bh & 7;
        int row = b_ * T + t_glob;          // B-MAJOR row
        int lslot = (row & 15) + ((q4 >> 1) << 4);
        int j0 = (q4 & 1) * 4;
        size_t fbase = (((size_t)(row >> 4) * 56 + h_) * 64 + lslot) * 8 + j0;
        const int masks[7] = {7, 3, 5, 6, 1, 2, 4};
        #pragma unroll
        for (int i = 0; i < 7; ++i) {
            int mm = masks[i];
            int live = (mm >> g) & 1;
            if (!(live | mixed)) continue;      // dead, never read by stage4
            float n0 = 0.f, n1 = 0.f, n2 = 0.f, n3 = 0.f, den = 0.f;
            if (mm & 1) { n0 += Pv[0][0]; n1 += Pv[0][1]; n2 += Pv[0][2]; n3 += Pv[0][3]; den += S[0]; }
            if (mm & 2) { n0 += Pv[1][0]; n1 += Pv[1][1]; n2 += Pv[1][2]; n3 += Pv[1][3]; den += S[1]; }
            if (mm & 4) { n0 += Pv[2][0]; n1 += Pv[2][1]; n2 += Pv[2][2]; n3 += Pv[2][3]; den += S[2]; }
            float r = 1.f / den;
            float o[4];
            o[0] = live ? n0 * r : 0.f;
            o[1] = live ? n1 * r : 0.f;
            o[2] = live ? n2 * r : 0.f;
            o[3] = live ? n3 * r : 0.f;
            ushort4 hi4, lo4;
            unsigned short* hp = (unsigned short*)&hi4;
            unsigned short* lp = (unsigned short*)&lo4;
            #pragma unroll
            for (int jq = 0; jq < 4; ++jq) {
                unsigned short hu = f2bf_u(o[jq]);
                hp[jq] = hu;
                lp[jq] = f2bf_u(o[jq] - bfu2f(hu));
            }
            size_t addr = fbase + (size_t)i * (8 * 64 * 8);
            *(ushort4*)&Ohi[addr] = hi4;
            *(ushort4*)&Olo[addr] = lo4;
        }
    } else {
        // ---- wcomb2 branch (DT hi/lo fragment-major) ----
        float (*AsT)[34] = (float(*)[34])&SMEM[0];       // 32x34
        float (*Bs)[34]  = (float(*)[34])&SMEM[1088];    // 32x34
        int f32 = detect_f32(query);
        int idx = blockIdx.x - 768;
        int bx = idx & 7;             // e tile 0..7
        int by = (idx >> 3) & 7;      // c tile 0..7
        int i  = idx >> 6;            // branch 0..6
        int tx = tid & 15, ty = tid >> 4;
        int colbase = bx * 32, rowbase = by * 32;
        float acc[2][2] = {};

        for (int kb = 0; kb < 8; ++kb) {
            __syncthreads();
            #pragma unroll
            for (int l = 0; l < 4; ++l) {
                int idx2 = l * 256 + tid;
                int c = idx2 & 31, kk = idx2 >> 5;
                AsT[kk][c] = Mtmp[(size_t)i * 65536 + (kb * 32 + kk) * 256 + rowbase + c];
                int k2 = idx2 & 31, n = idx2 >> 5;
                Bs[k2][n] = ldu(finalw, (size_t)(colbase + n) * 256 + kb * 32 + k2, f32);
            }
            __syncthreads();
            #pragma unroll 8
            for (int kk = 0; kk < 32; ++kk) {
                const float2 av = *(const float2*)&AsT[kk][ty * 2];
                const float2 bv = *(const float2*)&Bs[kk][tx * 2];
                acc[0][0] += av.x * bv.x; acc[0][1] += av.x * bv.y;
                acc[1][0] += av.y * bv.x; acc[1][1] += av.y * bv.y;
            }
        }
        #pragma unroll
        for (int u = 0; u < 2; ++u)
            #pragma unroll
            for (int v = 0; v < 2; ++v) {
                int c = rowbase + ty * 2 + u, e = colbase + tx * 2 + v;
                float a = acc[u][v];
                unsigned short hu = f2bf_u(a);
                size_t fidx = (((size_t)(e >> 4) * 56 + i * 8 + (c >> 5)) * 64
                               + (e & 15) + (((c >> 3) & 3) << 4)) * 8 + (c & 7);
                DThi[fidx] = hu;
                DTlo[fidx] = f2bf_u(a - bfu2f(hu));
            }
    }
}

// ---------------------------------------------------------------------------
// STAGE 4 (round-26 proven): result = O@Dstack + d0, B-MAJOR O rows,
// XCD-swizzled 1D grid.
// ---------------------------------------------------------------------------
__global__ __launch_bounds__(256) void final_gemm_mfma_kernel(
    const unsigned short* __restrict__ Ohi, const unsigned short* __restrict__ Olo,
    const unsigned short* __restrict__ DThi, const unsigned short* __restrict__ DTlo,
    const float* __restrict__ d0, const void* query,
    void* __restrict__ outv)
{
    int f32 = detect_f32(query);
    int bid = blockIdx.x;                 // 0..767
    int xcd = bid & 7, rr_ = bid >> 3;    // rr_ ∈ [0,96)
    int slot = rr_ >> 2, bx = rr_ & 3;    // slot ∈ [0,24)
    int by = slot * 8 + xcd;              // by ∈ [0,192), bijective
    int w  = threadIdx.x >> 6;
    int lane = threadIdx.x & 63;
    int m = lane & 15, quad = lane >> 4;
    int R0 = by * 16, C0 = bx * 64 + w * 16;

    // B-major rows: b = R0/768, t range [R0%768, R0%768+15] (16 | 768)
    int b_out = R0 / 768;
    int tfirst = R0 - b_out * 768;
    int g0 = (tfirst < 300) ? 0 : (tfirst < 550 ? 1 : 2);
    int g1 = (tfirst + 15 < 300) ? 0 : (tfirst + 15 < 550 ? 1 : 2);
    int activeset = (1 << g0) | (1 << g1);
    const int masks[7] = {7, 3, 5, 6, 1, 2, 4};

    const unsigned short* Abase_h = Ohi + (size_t)by * 56 * 512 + lane * 8;
    const unsigned short* Abase_l = Olo + (size_t)by * 56 * 512 + lane * 8;
    const unsigned short* Bbase_h = DThi + (size_t)(bx * 4 + w) * 56 * 512 + lane * 8;
    const unsigned short* Bbase_l = DTlo + (size_t)(bx * 4 + w) * 56 * 512 + lane * 8;

    f32x4 acc = {};
    for (int i = 0; i < 7; ++i) {
        if (!(masks[i] & activeset)) continue;
        #pragma unroll
        for (int kb = 0; kb < 8; ++kb) {
            size_t off = (size_t)(i * 8 + kb) * 512;
            bf16x8 ah = *(const bf16x8*)(Abase_h + off);
            bf16x8 al = *(const bf16x8*)(Abase_l + off);
            bf16x8 bh = *(const bf16x8*)(Bbase_h + off);
            bf16x8 bl = *(const bf16x8*)(Bbase_l + off);
            acc = __builtin_amdgcn_mfma_f32_16x16x32_bf16(ah, bh, acc, 0, 0, 0);
            acc = __builtin_amdgcn_mfma_f32_16x16x32_bf16(ah, bl, acc, 0, 0, 0);
            acc = __builtin_amdgcn_mfma_f32_16x16x32_bf16(al, bh, acc, 0, 0, 0);
        }
    }
    float dv = d0[C0 + m];
    #pragma unroll
    for (int r = 0; r < 4; ++r) {
        int t = tfirst + quad * 4 + r;
        int col = C0 + m;
        float val = acc[r] + dv;
        size_t orow = (size_t)t * B + b_out;        // back to (t,b) row order
        if (f32) ((float*)outv)[orow * 256 + col] = val;
        else ((__hip_bfloat16*)outv)[orow * 256 + col] = __float2bfloat16(val);
    }
}

// ---------------------------------------------------------------------------
extern "C" void kernel_launch(void* const* d_in, const int* in_sizes, int n_in,
                              void* d_out, int out_size, void* d_ws, size_t ws_size,
                              hipStream_t stream) {
    const void* query     = d_in[0];
    const void* key       = d_in[1];
    const void* value     = d_in[2];
    const void* in_proj_w = d_in[3];
    const void* in_proj_b = d_in[4];
    const void* out_w     = d_in[5];
    const void* out_b     = d_in[6];
    const void* s_l_w     = d_in[7];
    const void* s_l_b     = d_in[8];
    const void* s_a_w     = d_in[9];
    const void* s_a_b     = d_in[10];
    const void* s_v_w     = d_in[11];
    const void* s_v_b     = d_in[12];
    const void* final_w   = d_in[13];
    const void* final_b   = d_in[14];

    float* ws     = (float*)d_ws;
    float* qws    = ws;                 //   786432 f (q fp32)
    unsigned short* KRh = (unsigned short*)(ws + 786432);   // K rows [bh][s][hd]
    unsigned short* KRl = KRh + 786432;
    unsigned short* VFh = (unsigned short*)(ws + 1572864);  // V frag-major
    unsigned short* VFl = VFh + 786432;
    // O region [2359296, 7864320): Ohi/Olo for attn+final; aliased by the
    // conversion buffers WF/GF/OWF (consumed before attn writes O).
    unsigned short* Ohi = (unsigned short*)(ws + 2359296);   // 5505024 bf16
    unsigned short* Olo = (unsigned short*)(ws + 5111808);   // 5505024 bf16
    unsigned short* WFh = (unsigned short*)(ws + 2359296);   //  196608 bf16
    unsigned short* WFl = WFh + 196608;                      //  196608 bf16
    unsigned short* GFh = (unsigned short*)(ws + 4915200);   //  458752 bf16
    unsigned short* GFl = GFh + 458752;
    unsigned short* OWFh = GFl + 458752;                     //  458752 bf16
    unsigned short* OWFl = OWFh + 458752;                    // ends f 5832704
    float* Mtmp   = ws + 7864320;       //   458752 f
    unsigned short* DThi = (unsigned short*)(ws + 8323072);  // 458752 bf16
    unsigned short* DTlo = (unsigned short*)(ws + 8552448);  // 458752 bf16
    float* d0     = ws + 8781824;       //      256 f
    float* c0     = ws + 8782336;       //      256 f

    stage1_kernel<<<800, 256, 0, stream>>>(query, in_proj_w,
                                           s_l_w, s_a_w, s_v_w, out_w,
                                           out_b, s_l_b, s_a_b, s_v_b,
                                           WFh, WFl,
                                           GFh, GFl, OWFh, OWFl, c0);
    stage2_kernel<<<1280, 256, 0, stream>>>(query, key, value,
                                            WFh, WFl, in_proj_b, qws,
                                            KRh, KRl, VFh, VFl,
                                            GFh, GFl, OWFh, OWFl, Mtmp,
                                            c0, final_w, final_b, d0);
    stage3_kernel<<<1216, 256, 0, stream>>>(qws, KRh, KRl, VFh, VFl,
                                            Ohi, Olo,
                                            Mtmp, final_w, query,
                                            DThi, DTlo);
    final_gemm_mfma_kernel<<<768, 256, 0, stream>>>(Ohi, Olo, DThi, DTlo,
                                                    d0, query, d_out);
}